// Round 2
// baseline (190.011 us; speedup 1.0000x reference)
//
#include <hip/hip_runtime.h>

// mean(( (model-cur)/3 - 0.0257*Lap3D(cur) - src(cur) )^2) over [8,1,128,128,128] f32.
// Zero-padded 7-point stencil.
//
// Thread decomposition: each thread owns a z-column of 8 steps at fixed (b,y,x4),
// processing one float4 (4 W-elements) per step. Z-march reuses the center plane
// register as next step's z-minus plane. X-neighbors come from wave shuffles.

constexpr int DD = 128;
constexpr int HH = 128;
constexpr int WW = 128;
constexpr long long N_ELEM = 8LL * DD * HH * WW;   // 16,777,216
constexpr int ZSTEP = 8;
constexpr int NBLOCKS = 2048;                      // 2048*256 threads * 8 steps * 4 elems = N_ELEM

constexpr float ALPHA  = 0.0257f;
constexpr float INV_DT = 1.0f / 3.0f;
constexpr float SRC_I  = 100000.0f;
constexpr float THRESH = 1000.0f;

__global__ __launch_bounds__(256, 4) void heat_loss_kernel(
        const float* __restrict__ model,
        const float* __restrict__ cur,
        float* __restrict__ block_sums) {
    const int tid = blockIdx.x * blockDim.x + threadIdx.x;   // 0 .. 524287
    const int x4 = tid & 31;                                  // vec position in row
    int rest = tid >> 5;
    const int y = rest & 127;
    rest >>= 7;
    const int zblk = rest & 15;
    const int b = rest >> 4;
    const int z0 = zblk * ZSTEP;

    int i = ((b * DD + z0) * HH + y) * WW + x4 * 4;           // flat f32 index, < 2^24

    const bool y_lo = (y == 0);
    const bool y_hi = (y == 127);
    const bool x_lo = (x4 == 0);
    const bool x_hi = (x4 == 31);
    const float4 zero4 = make_float4(0.f, 0.f, 0.f, 0.f);

    float4 c  = *reinterpret_cast<const float4*>(cur + i);
    float4 zm = (z0 == 0) ? zero4
                          : *reinterpret_cast<const float4*>(cur + i - HH * WW);

    float acc = 0.0f;

    #pragma unroll
    for (int s = 0; s < ZSTEP; ++s) {
        const bool z_hi = (z0 + s == 127);
        const float4 zp = z_hi ? zero4
                               : *reinterpret_cast<const float4*>(cur + i + HH * WW);
        const float4 m  = *reinterpret_cast<const float4*>(model + i);
        const float4 ym = y_lo ? zero4
                               : *reinterpret_cast<const float4*>(cur + i - WW);
        const float4 yp = y_hi ? zero4
                               : *reinterpret_cast<const float4*>(cur + i + WW);

        // x-neighbors via wave shuffle. Lanes with x4==0 are exactly lanes 0 and 32,
        // so the cross-row leak at the 32-lane boundary is always zeroed.
        float left  = __shfl_up(c.w, 1, 64);
        float right = __shfl_down(c.x, 1, 64);
        if (x_lo) left = 0.0f;
        if (x_hi) right = 0.0f;

        const float cc[4] = {c.x, c.y, c.z, c.w};
        const float mm[4] = {m.x, m.y, m.z, m.w};
        const float xs[6] = {left, c.x, c.y, c.z, c.w, right};
        const float yms[4] = {ym.x, ym.y, ym.z, ym.w};
        const float yps[4] = {yp.x, yp.y, yp.z, yp.w};
        const float zms[4] = {zm.x, zm.y, zm.z, zm.w};
        const float zps[4] = {zp.x, zp.y, zp.z, zp.w};

        #pragma unroll
        for (int j = 0; j < 4; ++j) {
            const float lap = xs[j] + xs[j + 2] + yms[j] + yps[j]
                            + zms[j] + zps[j] - 6.0f * cc[j];
            const float td  = (mm[j] - cc[j]) * INV_DT;
            const float src = (cc[j] > THRESH) ? SRC_I : 0.0f;
            const float r   = td - ALPHA * lap - src;
            acc = fmaf(r, r, acc);
        }

        zm = c;
        c  = zp;
        i += HH * WW;
    }

    // 64-lane wave reduction
    #pragma unroll
    for (int off = 32; off > 0; off >>= 1)
        acc += __shfl_down(acc, off, 64);

    __shared__ float wsum[4];
    const int lane = threadIdx.x & 63;
    const int wave = threadIdx.x >> 6;
    if (lane == 0) wsum[wave] = acc;
    __syncthreads();

    if (threadIdx.x == 0)
        block_sums[blockIdx.x] = wsum[0] + wsum[1] + wsum[2] + wsum[3];
}

__global__ __launch_bounds__(256) void finalize_kernel(
        const float* __restrict__ block_sums, float* __restrict__ out) {
    double a = 0.0;
    for (int j = threadIdx.x; j < NBLOCKS; j += 256)
        a += (double)block_sums[j];

    #pragma unroll
    for (int off = 32; off > 0; off >>= 1)
        a += __shfl_down(a, off, 64);

    __shared__ double wsum[4];
    const int lane = threadIdx.x & 63;
    const int wave = threadIdx.x >> 6;
    if (lane == 0) wsum[wave] = a;
    __syncthreads();

    if (threadIdx.x == 0)
        out[0] = (float)((wsum[0] + wsum[1] + wsum[2] + wsum[3]) / (double)N_ELEM);
}

extern "C" void kernel_launch(void* const* d_in, const int* in_sizes, int n_in,
                              void* d_out, int out_size, void* d_ws, size_t ws_size,
                              hipStream_t stream) {
    const float* model = (const float*)d_in[0];   // model_output
    const float* cur   = (const float*)d_in[1];   // current_input
    float* block_sums = (float*)d_ws;             // NBLOCKS floats, fully written each call
    float* out = (float*)d_out;

    heat_loss_kernel<<<NBLOCKS, 256, 0, stream>>>(model, cur, block_sums);
    finalize_kernel<<<1, 256, 0, stream>>>(block_sums, out);
}

// Round 4
// 146.511 us; speedup vs baseline: 1.2969x; 1.2969x over previous
//
#include <hip/hip_runtime.h>

// mean(( (model-cur)/3 - 0.0257*Lap3D(cur) - src(cur) )^2) over [8,1,128,128,128] f32.
// Zero-padded 7-point stencil.
//
// Decomposition: thread tid owns (z,y,x4) fixed across all 8 batches
// (grid-stride of 2^19 threads leaves z,y,x4 invariant; only b changes).
// All boundary handling is precomputed: clamped offsets + 0/1 float masks,
// so every load is unconditional and the compiler can batch them.
// Manual 2x unroll: 12 float4 loads in flight per iteration pair.

constexpr int WW = 128;
constexpr int HH = 128;
constexpr int DD = 128;
constexpr long long N_ELEM = 8LL * DD * HH * WW;   // 16,777,216
constexpr int NBLOCKS = 2048;

constexpr float ALPHA  = 0.0257f;
constexpr float INV_DT = 1.0f / 3.0f;
constexpr float SRC_I  = 100000.0f;
constexpr float THRESH = 1000.0f;

__device__ __forceinline__ float sq_residual4(
        const float4 c, const float4 m,
        const float4 ym, const float4 yp,
        const float4 zm, const float4 zp,
        const float fym, const float fyp, const float fzm, const float fzp,
        const bool x_lo, const bool x_hi, float acc) {
    // x-neighbors via wave shuffle; lanes with x4==0 are lanes {0,32}, x4==31 are {31,63},
    // so the 32-lane-boundary leak is always masked.
    float left  = __shfl_up(c.w, 1, 64);
    float right = __shfl_down(c.x, 1, 64);
    if (x_lo) left = 0.0f;
    if (x_hi) right = 0.0f;

    const float cc[4]  = {c.x, c.y, c.z, c.w};
    const float mm[4]  = {m.x, m.y, m.z, m.w};
    const float xs[6]  = {left, c.x, c.y, c.z, c.w, right};
    const float yms[4] = {ym.x, ym.y, ym.z, ym.w};
    const float yps[4] = {yp.x, yp.y, yp.z, yp.w};
    const float zms[4] = {zm.x, zm.y, zm.z, zm.w};
    const float zps[4] = {zp.x, zp.y, zp.z, zp.w};

    #pragma unroll
    for (int j = 0; j < 4; ++j) {
        float lap = xs[j] + xs[j + 2] - 6.0f * cc[j];
        lap = fmaf(fym, yms[j], lap);
        lap = fmaf(fyp, yps[j], lap);
        lap = fmaf(fzm, zms[j], lap);
        lap = fmaf(fzp, zps[j], lap);
        const float td  = (mm[j] - cc[j]) * INV_DT;
        const float src = (cc[j] > THRESH) ? SRC_I : 0.0f;
        const float r   = td - ALPHA * lap - src;
        acc = fmaf(r, r, acc);
    }
    return acc;
}

__global__ __launch_bounds__(256) void heat_loss_kernel(
        const float* __restrict__ model,
        const float* __restrict__ cur,
        float* __restrict__ block_sums) {
    const int tid = blockIdx.x * blockDim.x + threadIdx.x;   // 0 .. 2^19-1
    const int x4 = tid & 31;
    const int y  = (tid >> 5) & 127;
    const int z  = (tid >> 12) & 127;

    const bool x_lo = (x4 == 0);
    const bool x_hi = (x4 == 31);
    const float fym = (y == 0)   ? 0.0f : 1.0f;
    const float fyp = (y == 127) ? 0.0f : 1.0f;
    const float fzm = (z == 0)   ? 0.0f : 1.0f;
    const float fzp = (z == 127) ? 0.0f : 1.0f;
    const int off_ym = (y == 0)   ? 0 : -WW;
    const int off_yp = (y == 127) ? 0 :  WW;
    const int off_zm = (z == 0)   ? 0 : -HH * WW;
    const int off_zp = (z == 127) ? 0 :  HH * WW;

    int i = (z * HH + y) * WW + x4 * 4;    // batch-0 flat index; +2^21 per batch

    float acc = 0.0f;

    #pragma unroll 1
    for (int bb = 0; bb < 4; ++bb) {
        const int i0 = i;
        const int i1 = i + (1 << 21);

        // issue all 12 loads before any compute
        const float4 c0  = *reinterpret_cast<const float4*>(cur   + i0);
        const float4 m0  = *reinterpret_cast<const float4*>(model + i0);
        const float4 ym0 = *reinterpret_cast<const float4*>(cur   + i0 + off_ym);
        const float4 yp0 = *reinterpret_cast<const float4*>(cur   + i0 + off_yp);
        const float4 zm0 = *reinterpret_cast<const float4*>(cur   + i0 + off_zm);
        const float4 zp0 = *reinterpret_cast<const float4*>(cur   + i0 + off_zp);
        const float4 c1  = *reinterpret_cast<const float4*>(cur   + i1);
        const float4 m1  = *reinterpret_cast<const float4*>(model + i1);
        const float4 ym1 = *reinterpret_cast<const float4*>(cur   + i1 + off_ym);
        const float4 yp1 = *reinterpret_cast<const float4*>(cur   + i1 + off_yp);
        const float4 zm1 = *reinterpret_cast<const float4*>(cur   + i1 + off_zm);
        const float4 zp1 = *reinterpret_cast<const float4*>(cur   + i1 + off_zp);

        acc = sq_residual4(c0, m0, ym0, yp0, zm0, zp0, fym, fyp, fzm, fzp, x_lo, x_hi, acc);
        acc = sq_residual4(c1, m1, ym1, yp1, zm1, zp1, fym, fyp, fzm, fzp, x_lo, x_hi, acc);

        i += (1 << 22);
    }

    // 64-lane wave reduction
    #pragma unroll
    for (int off = 32; off > 0; off >>= 1)
        acc += __shfl_down(acc, off, 64);

    __shared__ float wsum[4];
    const int lane = threadIdx.x & 63;
    const int wave = threadIdx.x >> 6;
    if (lane == 0) wsum[wave] = acc;
    __syncthreads();

    if (threadIdx.x == 0)
        block_sums[blockIdx.x] = wsum[0] + wsum[1] + wsum[2] + wsum[3];
}

__global__ __launch_bounds__(256) void finalize_kernel(
        const float* __restrict__ block_sums, float* __restrict__ out) {
    double a = 0.0;
    for (int j = threadIdx.x; j < NBLOCKS; j += 256)
        a += (double)block_sums[j];

    #pragma unroll
    for (int off = 32; off > 0; off >>= 1)
        a += __shfl_down(a, off, 64);

    __shared__ double wsum[4];
    const int lane = threadIdx.x & 63;
    const int wave = threadIdx.x >> 6;
    if (lane == 0) wsum[wave] = a;
    __syncthreads();

    if (threadIdx.x == 0)
        out[0] = (float)((wsum[0] + wsum[1] + wsum[2] + wsum[3]) / (double)N_ELEM);
}

extern "C" void kernel_launch(void* const* d_in, const int* in_sizes, int n_in,
                              void* d_out, int out_size, void* d_ws, size_t ws_size,
                              hipStream_t stream) {
    const float* model = (const float*)d_in[0];   // model_output
    const float* cur   = (const float*)d_in[1];   // current_input
    float* block_sums = (float*)d_ws;             // NBLOCKS floats, fully written each call
    float* out = (float*)d_out;

    heat_loss_kernel<<<NBLOCKS, 256, 0, stream>>>(model, cur, block_sums);
    finalize_kernel<<<1, 256, 0, stream>>>(block_sums, out);
}